// Round 3
// baseline (319.579 us; speedup 1.0000x reference)
//
#include <hip/hip_runtime.h>
#include <math.h>

#define NN 4
#define TMAX 20
#define EPS 1e-6f
#define POST_MULT 2.0f

typedef float vfloat4 __attribute__((ext_vector_type(4)));

// ---------------------------------------------------------------------------
// Fused kernel: one block per t (round-1 structure, best measured at 107 us).
// SINGLE-VARIABLE CHANGE vs round 1: plain stores instead of
// __builtin_nontemporal_store. Rounds 0/1/2 (three different structures,
// occupancy 30-48%) all capped at ~2.3 TB/s with NT stores while the
// harness's fill kernel sustains 6.5 TB/s of normal-path writes on the same
// run -> theory: the NT write path is the throughput cap, not structure.
//   Phase 1 (lanes 0..15 of wave 0): shuffle-based Sinkhorn -> 96 B LDS.
//   Phase 2 (all 256 threads): one vfloat4 strip per thread, 5 loads,
//   5 stores.
// ---------------------------------------------------------------------------
__global__ __launch_bounds__(256) void fused_kernel(
    const float* __restrict__ x,          // (T, 4, C)
    const float* __restrict__ f_out,      // (T, C)
    const float* __restrict__ mix,        // (T, 24)
    const float* __restrict__ invr,       // (T,)
    const float* __restrict__ alpha_pre,  // (1,)
    const float* __restrict__ alpha_post, // (1,)
    const float* __restrict__ alpha_res,  // (1,)
    const float* __restrict__ bias,       // (24,)
    float* __restrict__ y_pre,            // (T, C)
    float* __restrict__ out,              // (T, 4, C)
    int C)
{
    __shared__ float sm[24];

    const int t   = blockIdx.x;
    const int tid = threadIdx.x;

    // --- Phase 1: coefficients (lanes 0..15 of wave 0 only) ---
    if (tid < 16) {
        const int lane = tid;              // flat index i*4+j
        const float ir = invr[t];

        float r = mix[t * 24 + 8 + lane] * ir * alpha_res[0] + bias[8 + lane];
        float m = r;
        m = fmaxf(m, __shfl_xor(m, 1));
        m = fmaxf(m, __shfl_xor(m, 2));
        r = __expf(r - m);
        #pragma unroll
        for (int it = 0; it < TMAX; ++it) {
            float rs = r;                   // row sum (over j)
            rs += __shfl_xor(rs, 1);
            rs += __shfl_xor(rs, 2);
            r = r / (rs + EPS);
            float cs = r;                   // col sum (over i)
            cs += __shfl_xor(cs, 4);
            cs += __shfl_xor(cs, 8);
            r = r / (cs + EPS);
        }
        sm[8 + lane] = r;

        if (lane < 8) {
            const float a = (lane < NN) ? alpha_pre[0] : alpha_post[0];
            const float z = mix[t * 24 + lane] * ir * a + bias[lane];
            float sg = 1.0f / (1.0f + __expf(-z));
            if (lane >= NN) sg *= POST_MULT;
            sm[lane] = sg;
        }
    }
    __syncthreads();

    // --- Phase 2: streaming (all threads) ---
    const float hp0 = sm[0], hp1 = sm[1], hp2 = sm[2], hp3 = sm[3];
    const float hq0 = sm[4], hq1 = sm[5], hq2 = sm[6], hq3 = sm[7];
    float hr[NN][NN];  // hr[j][i] = h_res[j][i] = sm[8 + j*4 + i]
    #pragma unroll
    for (int j = 0; j < NN; ++j)
        #pragma unroll
        for (int i = 0; i < NN; ++i)
            hr[j][i] = sm[8 + j * 4 + i];

    const int NV = C >> 2;
    const vfloat4* xv4 = (const vfloat4*)(x + (size_t)t * NN * C);
    const vfloat4* fv4 = (const vfloat4*)(f_out + (size_t)t * C);
    vfloat4* yp4 = (vfloat4*)(y_pre + (size_t)t * C);
    vfloat4* o4  = (vfloat4*)(out + (size_t)t * NN * C);

    for (int v = tid; v < NV; v += blockDim.x) {
        vfloat4 xv[NN];
        #pragma unroll
        for (int n = 0; n < NN; ++n) xv[n] = xv4[n * NV + v];
        const vfloat4 fv = fv4[v];

        // y_pre = sum_n h_pre[n] * x[n]
        vfloat4 yv = hp0 * xv[0] + hp1 * xv[1] + hp2 * xv[2] + hp3 * xv[3];
        yp4[v] = yv;

        // out[j] = sum_i hr[j][i] * x[i] + h_post[j] * f_out
        const float hq[NN] = {hq0, hq1, hq2, hq3};
        #pragma unroll
        for (int j = 0; j < NN; ++j) {
            vfloat4 ov = hq[j] * fv;
            #pragma unroll
            for (int i = 0; i < NN; ++i) ov += hr[j][i] * xv[i];
            o4[j * NV + v] = ov;
        }
    }
}

extern "C" void kernel_launch(void* const* d_in, const int* in_sizes, int n_in,
                              void* d_out, int out_size, void* d_ws, size_t ws_size,
                              hipStream_t stream) {
    const float* x          = (const float*)d_in[0];
    const float* f_out      = (const float*)d_in[1];
    const float* mix        = (const float*)d_in[2];
    const float* invr       = (const float*)d_in[3];
    const float* alpha_pre  = (const float*)d_in[4];
    const float* alpha_post = (const float*)d_in[5];
    const float* alpha_res  = (const float*)d_in[6];
    const float* bias       = (const float*)d_in[7];

    const int T = in_sizes[3];               // invr is (T,)
    const int C = in_sizes[1] / T;           // f_out is (T, C)

    float* y_pre = (float*)d_out;                   // (T, C)
    float* out   = (float*)d_out + (size_t)T * C;   // (T, N, C)
    (void)d_ws; (void)ws_size;                      // no workspace needed

    fused_kernel<<<T, 256, 0, stream>>>(x, f_out, mix, invr, alpha_pre,
                                        alpha_post, alpha_res, bias,
                                        y_pre, out, C);
}

// Round 4
// 305.013 us; speedup vs baseline: 1.0478x; 1.0478x over previous
//
#include <hip/hip_runtime.h>
#include <math.h>

#define NN 4
#define TMAX 20
#define EPS 1e-6f
#define POST_MULT 2.0f
#define KS 4   // v-strips per thread (NV=256 / 64 lanes)

typedef float vfloat4 __attribute__((ext_vector_type(4)));

// ---------------------------------------------------------------------------
// One SINGLE-WAVE (64-thread) block per t; each thread owns KS=4 vfloat4
// strips. Structure chosen from round-1/2/3 evidence: all prior kernels were
// latency-bound at ~2.2 TB/s because each thread had exactly ONE trip (5
// loads -> dependent stores -> die) and the Sinkhorn chain serialized in
// front of the loads.
//   1. FIRST instructions: issue all 20 independent b128 loads (4 strips x
//      {4 x + 1 f_out}) -- 4x MLP, straight-line so the compiler cannot sink
//      them (round-2's loop-carried-copy pipeline collapsed to 40 VGPRs).
//   2. Sinkhorn on lanes 0..15 runs UNDER the load latency.
//   3. Single-wave barrier (~free), broadcast coeffs from LDS, compute,
//      nontemporal stores (NT proven +10% vs plain in round 3).
// ---------------------------------------------------------------------------
__global__ __launch_bounds__(64) void fused_kernel(
    const float* __restrict__ x,          // (T, 4, C)
    const float* __restrict__ f_out,      // (T, C)
    const float* __restrict__ mix,        // (T, 24)
    const float* __restrict__ invr,       // (T,)
    const float* __restrict__ alpha_pre,  // (1,)
    const float* __restrict__ alpha_post, // (1,)
    const float* __restrict__ alpha_res,  // (1,)
    const float* __restrict__ bias,       // (24,)
    float* __restrict__ y_pre,            // (T, C)
    float* __restrict__ out,              // (T, 4, C)
    int C)
{
    __shared__ float sm[24];

    const int t   = blockIdx.x;
    const int tid = threadIdx.x;          // 0..63
    const int NV  = C >> 2;               // vfloat4 strips per row (256)

    const vfloat4* xv4 = (const vfloat4*)(x + (size_t)t * NN * C);
    const vfloat4* fv4 = (const vfloat4*)(f_out + (size_t)t * C);

    // --- 1. Issue ALL loads first (independent of everything below) ---
    vfloat4 xv[KS][NN];
    vfloat4 fv[KS];
    #pragma unroll
    for (int k = 0; k < KS; ++k) {
        const int v = tid + (k << 6);
        if (v < NV) {
            #pragma unroll
            for (int n = 0; n < NN; ++n) xv[k][n] = xv4[n * NV + v];
            fv[k] = fv4[v];
        }
    }

    // --- 2. Sinkhorn + gates on lanes 0..15, overlapping load latency ---
    if (tid < 16) {
        const int lane = tid;              // flat index i*4+j
        const float ir = invr[t];

        float r = mix[t * 24 + 8 + lane] * ir * alpha_res[0] + bias[8 + lane];
        float m = r;
        m = fmaxf(m, __shfl_xor(m, 1));
        m = fmaxf(m, __shfl_xor(m, 2));
        r = __expf(r - m);
        #pragma unroll
        for (int it = 0; it < TMAX; ++it) {
            float rs = r;                   // row sum (over j)
            rs += __shfl_xor(rs, 1);
            rs += __shfl_xor(rs, 2);
            r = r / (rs + EPS);
            float cs = r;                   // col sum (over i)
            cs += __shfl_xor(cs, 4);
            cs += __shfl_xor(cs, 8);
            r = r / (cs + EPS);
        }
        sm[8 + lane] = r;

        if (lane < 8) {
            const float a = (lane < NN) ? alpha_pre[0] : alpha_post[0];
            const float z = mix[t * 24 + lane] * ir * a + bias[lane];
            float sg = 1.0f / (1.0f + __expf(-z));
            if (lane >= NN) sg *= POST_MULT;
            sm[lane] = sg;
        }
    }
    __syncthreads();   // single-wave block: just a waitcnt + cheap barrier

    // --- 3. Broadcast coeffs, compute, NT-store ---
    const float hp0 = sm[0], hp1 = sm[1], hp2 = sm[2], hp3 = sm[3];
    const float hq[NN] = {sm[4], sm[5], sm[6], sm[7]};
    float hr[NN][NN];  // hr[j][i] = h_res[j][i] = sm[8 + j*4 + i]
    #pragma unroll
    for (int j = 0; j < NN; ++j)
        #pragma unroll
        for (int i = 0; i < NN; ++i)
            hr[j][i] = sm[8 + j * 4 + i];

    vfloat4* yp4 = (vfloat4*)(y_pre + (size_t)t * C);
    vfloat4* o4  = (vfloat4*)(out + (size_t)t * NN * C);

    #pragma unroll
    for (int k = 0; k < KS; ++k) {
        const int v = tid + (k << 6);
        if (v < NV) {
            // y_pre = sum_n h_pre[n] * x[n]
            vfloat4 yv = hp0 * xv[k][0] + hp1 * xv[k][1]
                       + hp2 * xv[k][2] + hp3 * xv[k][3];
            __builtin_nontemporal_store(yv, &yp4[v]);

            // out[j] = sum_i hr[j][i] * x[i] + h_post[j] * f_out
            #pragma unroll
            for (int j = 0; j < NN; ++j) {
                vfloat4 ov = hq[j] * fv[k];
                #pragma unroll
                for (int i = 0; i < NN; ++i) ov += hr[j][i] * xv[k][i];
                __builtin_nontemporal_store(ov, &o4[j * NV + v]);
            }
        }
    }
}

extern "C" void kernel_launch(void* const* d_in, const int* in_sizes, int n_in,
                              void* d_out, int out_size, void* d_ws, size_t ws_size,
                              hipStream_t stream) {
    const float* x          = (const float*)d_in[0];
    const float* f_out      = (const float*)d_in[1];
    const float* mix        = (const float*)d_in[2];
    const float* invr       = (const float*)d_in[3];
    const float* alpha_pre  = (const float*)d_in[4];
    const float* alpha_post = (const float*)d_in[5];
    const float* alpha_res  = (const float*)d_in[6];
    const float* bias       = (const float*)d_in[7];

    const int T = in_sizes[3];               // invr is (T,)
    const int C = in_sizes[1] / T;           // f_out is (T, C)

    float* y_pre = (float*)d_out;                   // (T, C)
    float* out   = (float*)d_out + (size_t)T * C;   // (T, N, C)
    (void)d_ws; (void)ws_size;                      // no workspace needed

    fused_kernel<<<T, 64, 0, stream>>>(x, f_out, mix, invr, alpha_pre,
                                       alpha_post, alpha_res, bias,
                                       y_pre, out, C);
}

// Round 5
// 302.571 us; speedup vs baseline: 1.0562x; 1.0081x over previous
//
#include <hip/hip_runtime.h>
#include <math.h>

#define NN 4
#define TMAX 20
#define EPS 1e-6f
#define POST_MULT 2.0f

typedef float vfloat4 __attribute__((ext_vector_type(4)));

// ---------------------------------------------------------------------------
// Kernel 1 (round-0 proven): 16 lanes per t, shuffle Sinkhorn, coeffs -> ws.
// Removes the serial Sinkhorn chain from the streaming kernel's critical
// path entirely. ~5 us.
// ---------------------------------------------------------------------------
__global__ __launch_bounds__(256) void coeff_kernel(
    const float* __restrict__ mix,        // (T, 24)
    const float* __restrict__ invr,       // (T,)
    const float* __restrict__ alpha_pre,  // (1,)
    const float* __restrict__ alpha_post, // (1,)
    const float* __restrict__ alpha_res,  // (1,)
    const float* __restrict__ bias,       // (24,)
    float* __restrict__ coeffs,           // (T, 24) in ws
    int T)
{
    const int gtid = blockIdx.x * blockDim.x + threadIdx.x;
    const int t    = gtid >> 4;
    const int lane = gtid & 15;
    if (t >= T) return;

    const float ir = invr[t];

    float r = mix[t * 24 + 8 + lane] * ir * alpha_res[0] + bias[8 + lane];
    float m = r;
    m = fmaxf(m, __shfl_xor(m, 1));
    m = fmaxf(m, __shfl_xor(m, 2));
    r = __expf(r - m);
    #pragma unroll
    for (int it = 0; it < TMAX; ++it) {
        float rs = r;                       // row sum (over j)
        rs += __shfl_xor(rs, 1);
        rs += __shfl_xor(rs, 2);
        r = r / (rs + EPS);
        float cs = r;                       // col sum (over i)
        cs += __shfl_xor(cs, 4);
        cs += __shfl_xor(cs, 8);
        r = r / (cs + EPS);
    }
    coeffs[t * 24 + 8 + lane] = r;

    if (lane < 8) {
        const float a = (lane < NN) ? alpha_pre[0] : alpha_post[0];
        const float z = mix[t * 24 + lane] * ir * a + bias[lane];
        float sg = 1.0f / (1.0f + __expf(-z));
        if (lane >= NN) sg *= POST_MULT;
        coeffs[t * 24 + lane] = sg;
    }
}

// ---------------------------------------------------------------------------
// One work item = one vfloat4 strip (t, v): 5 b128 loads, 21 vec FMAs,
// 5 NT b128 stores. Coefficients via readfirstlane -> scalar loads
// (t is wave-uniform because NV % 64 == 0).
// ---------------------------------------------------------------------------
__device__ __forceinline__ void process_item(
    long i, int sh, int NV,
    const float* __restrict__ x, const float* __restrict__ f_out,
    const float* __restrict__ coeffs,
    float* __restrict__ y_pre, float* __restrict__ out)
{
    const int t = (int)(i >> sh);
    const int v = (int)(i & (NV - 1));

    const int ts = __builtin_amdgcn_readfirstlane(t);
    const float* cf = coeffs + (size_t)ts * 24;

    const vfloat4* xv4 = (const vfloat4*)x + (size_t)t * NN * NV;
    const vfloat4* fv4 = (const vfloat4*)f_out + (size_t)t * NV;
    vfloat4* yp4 = (vfloat4*)y_pre + (size_t)t * NV;
    vfloat4* o4  = (vfloat4*)out + (size_t)t * NN * NV;

    vfloat4 xv[NN];
    #pragma unroll
    for (int n = 0; n < NN; ++n) xv[n] = xv4[n * NV + v];
    const vfloat4 fv = fv4[v];

    vfloat4 yv = cf[0] * xv[0] + cf[1] * xv[1] + cf[2] * xv[2] + cf[3] * xv[3];
    __builtin_nontemporal_store(yv, &yp4[v]);

    #pragma unroll
    for (int j = 0; j < NN; ++j) {
        vfloat4 ov = cf[4 + j] * fv;
        #pragma unroll
        for (int ii = 0; ii < NN; ++ii) ov += cf[8 + j * 4 + ii] * xv[ii];
        __builtin_nontemporal_store(ov, &o4[j * NV + v]);
    }
}

// ---------------------------------------------------------------------------
// Kernel 2: persistent grid-stride streaming (m13-copy shape: each wave does
// many trips, latency paid once, not per wave). Two INDEPENDENT items per
// loop iteration (i and i+M/2), straight-line, no guards -> >=10 b128 loads
// in flight per iteration; the compiler cannot sink them behind a branch.
// Requires NV power-of-2 and NV % 64 == 0 (launcher checks; fallback below).
// ---------------------------------------------------------------------------
__global__ __launch_bounds__(256) void stream_kernel(
    const float* __restrict__ x,       // (T, 4, C)
    const float* __restrict__ f_out,   // (T, C)
    const float* __restrict__ coeffs,  // (T, 24)
    float* __restrict__ y_pre,         // (T, C)
    float* __restrict__ out,           // (T, 4, C)
    int C, int T)
{
    const int NV = C >> 2;
    const int sh = 31 - __clz(NV);            // log2(NV), NV pow2 guaranteed
    const long M = (long)T << sh;             // total items
    const long half = M >> 1;                 // multiple of 64 (T even)
    const long stride = (long)gridDim.x * blockDim.x;
    const long gid = (long)blockIdx.x * blockDim.x + threadIdx.x;

    for (long i = gid; i < half; i += stride) {
        process_item(i,        sh, NV, x, f_out, coeffs, y_pre, out);
        process_item(i + half, sh, NV, x, f_out, coeffs, y_pre, out);
    }
    // generic odd-M tail (never taken for this shape)
    for (long i = (half << 1) + gid; i < M; i += stride)
        process_item(i, sh, NV, x, f_out, coeffs, y_pre, out);
}

// ---------------------------------------------------------------------------
// Fallback for non-pow2 / non-64-multiple NV: round-4 fused per-t kernel.
// ---------------------------------------------------------------------------
__global__ __launch_bounds__(256) void stream_fallback(
    const float* __restrict__ x, const float* __restrict__ f_out,
    const float* __restrict__ coeffs,
    float* __restrict__ y_pre, float* __restrict__ out, int C)
{
    const int t   = blockIdx.x;
    const int tid = threadIdx.x;
    const float* cf = coeffs + (size_t)t * 24;

    const int NV = C >> 2;
    const vfloat4* xv4 = (const vfloat4*)(x + (size_t)t * NN * C);
    const vfloat4* fv4 = (const vfloat4*)(f_out + (size_t)t * C);
    vfloat4* yp4 = (vfloat4*)(y_pre + (size_t)t * C);
    vfloat4* o4  = (vfloat4*)(out + (size_t)t * NN * C);

    for (int v = tid; v < NV; v += blockDim.x) {
        vfloat4 xv[NN];
        #pragma unroll
        for (int n = 0; n < NN; ++n) xv[n] = xv4[n * NV + v];
        const vfloat4 fv = fv4[v];

        vfloat4 yv = cf[0] * xv[0] + cf[1] * xv[1] + cf[2] * xv[2] + cf[3] * xv[3];
        __builtin_nontemporal_store(yv, &yp4[v]);

        #pragma unroll
        for (int j = 0; j < NN; ++j) {
            vfloat4 ov = cf[4 + j] * fv;
            #pragma unroll
            for (int i = 0; i < NN; ++i) ov += cf[8 + j * 4 + i] * xv[i];
            __builtin_nontemporal_store(ov, &o4[j * NV + v]);
        }
    }
}

extern "C" void kernel_launch(void* const* d_in, const int* in_sizes, int n_in,
                              void* d_out, int out_size, void* d_ws, size_t ws_size,
                              hipStream_t stream) {
    const float* x          = (const float*)d_in[0];
    const float* f_out      = (const float*)d_in[1];
    const float* mix        = (const float*)d_in[2];
    const float* invr       = (const float*)d_in[3];
    const float* alpha_pre  = (const float*)d_in[4];
    const float* alpha_post = (const float*)d_in[5];
    const float* alpha_res  = (const float*)d_in[6];
    const float* bias       = (const float*)d_in[7];

    const int T = in_sizes[3];               // invr is (T,)
    const int C = in_sizes[1] / T;           // f_out is (T, C)

    float* y_pre = (float*)d_out;                   // (T, C)
    float* out   = (float*)d_out + (size_t)T * C;   // (T, N, C)
    float* coeffs = (float*)d_ws;                   // (T, 24)

    const int grid1 = (T * 16 + 255) / 256;
    coeff_kernel<<<grid1, 256, 0, stream>>>(mix, invr, alpha_pre, alpha_post,
                                            alpha_res, bias, coeffs, T);

    const int NV = C >> 2;
    const bool fast = NV > 0 && (NV & (NV - 1)) == 0 && (NV % 64) == 0
                      && (T % 2) == 0;
    if (fast) {
        stream_kernel<<<2048, 256, 0, stream>>>(x, f_out, coeffs, y_pre, out,
                                                C, T);
    } else {
        stream_fallback<<<T, 256, 0, stream>>>(x, f_out, coeffs, y_pre, out, C);
    }
}